// Round 10
// baseline (259.878 us; speedup 1.0000x reference)
//
#include <hip/hip_runtime.h>
#include <hip/hip_bf16.h>
#include <math.h>

// ---------- helpers ----------
__device__ __forceinline__ unsigned short f2bf(float f) {
    union { float f; unsigned u; } c; c.f = f;
    unsigned r = c.u + 0x7fffu + ((c.u >> 16) & 1u);
    return (unsigned short)(r >> 16);
}
__device__ __forceinline__ float bfu(unsigned short u) {
    union { unsigned x; float f; } c; c.x = ((unsigned)u) << 16; return c.f;
}
__device__ __forceinline__ float gelu_t(float x) {
    float z = x * (1.59576912f + 0.07135481f * x * x);
    return x / (1.0f + __expf(-z));
}

typedef __bf16 bf16x8_t __attribute__((ext_vector_type(8)));
typedef float  f32x4_t  __attribute__((ext_vector_type(4)));
typedef unsigned short u16x8 __attribute__((ext_vector_type(8)));

#define AS1 __attribute__((address_space(1)))
#define AS3 __attribute__((address_space(3)))
__device__ __forceinline__ void g2lds16(const void* g, void* l) {
    __builtin_amdgcn_global_load_lds((const AS1 unsigned int*)g, (AS3 unsigned int*)l, 16, 0, 0);
}

// ---------- weights fp32 -> bf16, unified MFMA-fragment order; +bias packing ----------
// Fragment order (R9): lane L's 16B B-fragment at chunk*8192B + L*16B -> every
// weight ds_read_b128 is a contiguous 1024B wave-span (conflict-free).
// R14: w1 is gamma-scaled (LN2 fold — verified math from R8-R11 fused_mlp).
// Block 384 packs bqkv = [bq|bk|bv].
__global__ void cvt_all(const float* __restrict__ wq, const float* __restrict__ wk,
                        const float* __restrict__ wv, const float* __restrict__ wo,
                        const float* __restrict__ w1, const float* __restrict__ w2,
                        const float* __restrict__ ln2g,
                        const float* __restrict__ bq, const float* __restrict__ bk,
                        const float* __restrict__ bv, float* __restrict__ bqkv,
                        unsigned short* __restrict__ qkvp, unsigned short* __restrict__ wop,
                        unsigned short* __restrict__ w1p, unsigned short* __restrict__ w2p) {
    int fid = blockIdx.x * 256 + threadIdx.x;   // one 8-elem k-fragment per thread; 98304 weight frags
    if (fid >= 98304) {                          // bias block
        int i = fid - 98304;
        if (i < 768) bqkv[i] = (i < 256) ? bq[i] : (i < 512 ? bk[i - 256] : bv[i - 512]);
        return;
    }
    const float* src; unsigned short* dst; int n, kf, KC, isw1 = 0;
    if (fid < 24576) {           // qkv: n 0..767, K=256
        n = fid >> 5; kf = fid & 31; KC = 8;
        const float* w = (n < 256) ? wq : (n < 512 ? wk : wv);
        src = w + (size_t)(n & 255) * 256 + kf * 8; dst = qkvp;
    } else if (fid < 32768) {    // wo: n 0..255, K=256
        int fi = fid - 24576; n = fi >> 5; kf = fi & 31; KC = 8;
        src = wo + (size_t)n * 256 + kf * 8; dst = wop;
    } else if (fid < 65536) {    // w1 (gamma-scaled): n 0..1023, K=256
        int fi = fid - 32768; n = fi >> 5; kf = fi & 31; KC = 8;
        src = w1 + (size_t)n * 256 + kf * 8; dst = w1p; isw1 = 1;
    } else {                     // w2: n 0..255, K=1024
        int fi = fid - 65536; n = fi >> 7; kf = fi & 127; KC = 32;
        src = w2 + (size_t)n * 1024 + kf * 8; dst = w2p;
    }
    size_t oidx = (size_t)(((n >> 7) * KC + (kf >> 2)) * 4096)
                + ((n >> 4) & 7) * 512 + (kf & 3) * 128 + (n & 15) * 8;
    float4 a = *(const float4*)(src);
    float4 b = *(const float4*)(src + 4);
    if (isw1) {
        int k0 = kf * 8;
        float4 g0 = *(const float4*)(ln2g + k0);
        float4 g1 = *(const float4*)(ln2g + k0 + 4);
        a.x *= g0.x; a.y *= g0.y; a.z *= g0.z; a.w *= g0.w;
        b.x *= g1.x; b.y *= g1.y; b.z *= g1.z; b.w *= g1.w;
    }
    u16x8 o = { f2bf(a.x), f2bf(a.y), f2bf(a.z), f2bf(a.w),
                f2bf(b.x), f2bf(b.y), f2bf(b.z), f2bf(b.w) };
    *(u16x8*)(dst + oidx) = o;
}

// ---------- LN2-fold row sums: s1[n]=sum_k g[k]*w1[n][k]; b1p[n]=b1[n]+sum_k beta[k]*w1[n][k]
__global__ void prep_mlp(const float* __restrict__ w1, const float* __restrict__ ln2g,
                         const float* __restrict__ ln2b, const float* __restrict__ b1,
                         float* __restrict__ s1, float* __restrict__ b1p) {
    int n = blockIdx.x * 256 + threadIdx.x;   // 0..1023
    const float* wr = w1 + (size_t)n * 256;
    float ss = 0.f, sb = 0.f;
    #pragma unroll 4
    for (int k = 0; k < 256; k += 4) {
        float4 w = *(const float4*)(wr + k);
        float4 g = *(const float4*)(ln2g + k);
        float4 b = *(const float4*)(ln2b + k);
        ss += w.x * g.x + w.y * g.y + w.z * g.z + w.w * g.w;
        sb += w.x * b.x + w.y * b.y + w.z * b.z + w.w * b.w;
    }
    s1[n] = ss;
    b1p[n] = b1[n] + sb;
}

// ---------- LayerNorm; GATHER=1 fuses shift+window-partition ----------
template<int GATHER, int BF16IN>
__global__ void ln_kernel(const void* __restrict__ xv, const float* __restrict__ g,
                          const float* __restrict__ b, unsigned short* __restrict__ out) {
    int row  = blockIdx.x * 4 + (threadIdx.x >> 6);
    int lane = threadIdx.x & 63;
    int src;
    if (GATHER) {
        int bb = row >> 12;
        int rem = row & 4095;
        int winid = rem >> 6, tok = rem & 63;
        int wi = winid >> 3, wj = winid & 7;
        int ii = tok >> 3,  jj = tok & 7;
        int hh = (wi * 8 + ii + 4) & 63;     // roll(-4)
        int ww = (wj * 8 + jj + 4) & 63;
        src = (bb << 12) + hh * 64 + ww;
    } else {
        src = row;
    }
    float4 v;
    if (BF16IN) {
        ushort4 u = *(const ushort4*)((const unsigned short*)xv + (size_t)src * 256 + lane * 4);
        v.x = bfu(u.x); v.y = bfu(u.y); v.z = bfu(u.z); v.w = bfu(u.w);
    } else {
        v = *(const float4*)((const float*)xv + (size_t)src * 256 + lane * 4);
    }
    float s  = v.x + v.y + v.z + v.w;
    float s2 = v.x*v.x + v.y*v.y + v.z*v.z + v.w*v.w;
    #pragma unroll
    for (int off = 32; off > 0; off >>= 1) {
        s  += __shfl_xor(s,  off, 64);
        s2 += __shfl_xor(s2, off, 64);
    }
    float mean = s * (1.0f / 256.0f);
    float var  = s2 * (1.0f / 256.0f) - mean * mean;
    float rstd = rsqrtf(var + 1e-5f);
    int c0 = lane * 4;
    float4 gg  = *(const float4*)(g + c0);
    float4 bb4 = *(const float4*)(b + c0);
    ushort4 o;
    o.x = f2bf((v.x - mean) * rstd * gg.x + bb4.x);
    o.y = f2bf((v.y - mean) * rstd * gg.y + bb4.y);
    o.z = f2bf((v.z - mean) * rstd * gg.z + bb4.z);
    o.w = f2bf((v.w - mean) * rstd * gg.w + bb4.w);
    *(ushort4*)(out + (size_t)row * 256 + c0) = o;
}

// ---------- tiled MFMA GEMM: C[M,N] = A[M,K] * Bw[N,K]^T + bias ----------
// Proven 2-buffer BK=32 __syncthreads pipeline (R7/R13); fragment-ordered B;
// R6 wave-contiguous vectorized epilogue (WRITE_SIZE = ideal).
// MODE 0: bf16+bias          MODE 2: window-reverse scatter + fp32 residual -> bf16
// MODE 3: bf16 residual -> fp32 out
// MODE 4: qkv HEAD-MAJOR scatter [wg][sel][h][tok][32] (attn reads fully coalesced)
// MODE 5: LN2-fold + gelu -> bf16 (A = raw bf16 residual; per-block row stats
//         prologue; h = rst*acc - murs*s1[n] + b1p[n]; math verified R8-R11)
template<int MODE, int K>
__global__ __launch_bounds__(256, 4) void gemm_tile(
        const unsigned short* __restrict__ A,
        const unsigned short* __restrict__ Bp,   // fragment-permuted weights
        const float* __restrict__ bias,
        int M, int N,
        unsigned short* __restrict__ obf,
        float* __restrict__ of32,
        const void* __restrict__ addp) {
    __shared__ __align__(16) char smem_raw[34816];  // 33792 dbuf/C-stage + 1KB stats
    unsigned short* sm = (unsigned short*)smem_raw;
    float* cst = (float*)smem_raw;
    float* stats = (float*)(smem_raw + 33792);      // [0..127]=rst [128..255]=mu*rst
    const int t = threadIdx.x;
    const int lane = t & 63, wave = t >> 6;
    const int m0 = blockIdx.x * 128, n0 = blockIdx.y * 128;
    const int wm = (wave >> 1) * 64, wn = (wave & 1) * 64;
    const int lr = lane & 15, kg = lane >> 4;

    // ---- MODE 5 prologue: per-row LN stats over full K=256 row (L2-hot) ----
    if (MODE == 5) {
        const unsigned short* xp = A + (size_t)(m0 + (t >> 1)) * 256 + (t & 1) * 128;
        float s = 0.f, s2 = 0.f;
        #pragma unroll
        for (int f = 0; f < 16; ++f) {
            u16x8 xf = *(const u16x8*)(xp + f * 8);
            #pragma unroll
            for (int e = 0; e < 8; ++e) { float v = bfu(xf[e]); s += v; s2 += v * v; }
        }
        s  += __shfl_xor(s, 1, 64);
        s2 += __shfl_xor(s2, 1, 64);
        if ((t & 1) == 0) {
            float mean = s * (1.0f / 256.0f);
            float var  = s2 * (1.0f / 256.0f) - mean * mean;
            float rst  = rsqrtf(var + 1e-5f);
            stats[t >> 1] = rst;
            stats[128 + (t >> 1)] = mean * rst;
        }
    }

    f32x4_t acc[4][4];
    #pragma unroll
    for (int i = 0; i < 4; ++i)
        #pragma unroll
        for (int j = 0; j < 4; ++j) { acc[i][j][0]=0.f; acc[i][j][1]=0.f; acc[i][j][2]=0.f; acc[i][j][3]=0.f; }

    const unsigned short* ga  = A  + (size_t)(m0 + (t >> 2)) * K + (t & 3) * 8;
    const unsigned short* gbp = Bp + (size_t)blockIdx.y * (K / 32) * 4096 + t * 8;
    unsigned short* lA = sm + t * 8;
    unsigned short* lB = sm + 4096 + t * 8;

    const int NT = K / 32;
    g2lds16(ga,                  lA);
    g2lds16(ga + (size_t)64 * K, lA + 2048);
    g2lds16(gbp,                 lB);
    g2lds16(gbp + 2048,          lB + 2048);
    __syncthreads();

    #pragma unroll
    for (int k = 0; k < NT; ++k) {
        const int cur = k & 1;
        if (k + 1 < NT) {
            const int nx = cur ^ 1;
            g2lds16(ga + (k + 1) * 32,                  lA + nx * 8192);
            g2lds16(ga + (size_t)64 * K + (k + 1) * 32, lA + nx * 8192 + 2048);
            g2lds16(gbp + (size_t)(k + 1) * 4096,        lB + nx * 8192);
            g2lds16(gbp + (size_t)(k + 1) * 4096 + 2048, lB + nx * 8192 + 2048);
        }
        const unsigned short* Ab = sm + cur * 8192;
        const unsigned short* Bb = Ab + 4096;
        bf16x8_t af[4], bfr[4];
        #pragma unroll
        for (int i = 0; i < 4; ++i)
            af[i] = *(const bf16x8_t*)&Ab[(wm + i * 16 + lr) * 32 + kg * 8];
        #pragma unroll
        for (int j = 0; j < 4; ++j)
            bfr[j] = *(const bf16x8_t*)&Bb[(((wave & 1) * 4 + j) * 64 + lane) * 8];
        #pragma unroll
        for (int i = 0; i < 4; ++i)
            #pragma unroll
            for (int j = 0; j < 4; ++j)
                acc[i][j] = __builtin_amdgcn_mfma_f32_16x16x32_bf16(af[i], bfr[j], acc[i][j], 0, 0, 0);
        __syncthreads();
    }

    // ---- 2-pass vectorized epilogue, wave-contiguous stores (R6) ----
    #pragma unroll
    for (int pass = 0; pass < 2; ++pass) {
        if (pass) __syncthreads();
        if ((wave >> 1) == pass) {
            float* cw = cst + (kg * 4) * 132 + wn + lr;
            #pragma unroll
            for (int i = 0; i < 4; ++i)
                #pragma unroll
                for (int j = 0; j < 4; ++j)
                    #pragma unroll
                    for (int e = 0; e < 4; ++e)
                        cw[(i * 16 + e) * 132 + j * 16] = acc[i][j][e];
        }
        __syncthreads();
        const int rr = t >> 4;
        const int ch = t & 15;
        if (MODE == 0) {
            #pragma unroll
            for (int c = 0; c < 4; ++c) {
                int r = rr + c * 16;
                int grow = m0 + pass * 64 + r;
                const float* cr = cst + r * 132 + ch * 8;
                const float* bp = bias + n0 + ch * 8;
                float4 a   = *(const float4*)(cr);
                float4 b4  = *(const float4*)(cr + 4);
                float4 ba  = *(const float4*)(bp);
                float4 bb4 = *(const float4*)(bp + 4);
                u16x8 o = { f2bf(a.x + ba.x),  f2bf(a.y + ba.y),  f2bf(a.z + ba.z),  f2bf(a.w + ba.w),
                            f2bf(b4.x + bb4.x), f2bf(b4.y + bb4.y), f2bf(b4.z + bb4.z), f2bf(b4.w + bb4.w) };
                *(u16x8*)(obf + (size_t)grow * N + n0 + ch * 8) = o;
            }
        } else if (MODE == 4) {   // qkv head-major: [wg][sel][h][tok][32]
            #pragma unroll
            for (int c = 0; c < 4; ++c) {
                int r = rr + c * 16;
                int grow = m0 + pass * 64 + r;
                int wgq = grow >> 6, tok = grow & 63;
                int cc = n0 + ch * 8;
                int sel = cc >> 8, hh = (cc >> 5) & 7, d = cc & 31;
                size_t dst = ((size_t)(wgq * 3 + sel) * 8 + hh) * 2048 + tok * 32 + d;
                const float* cr = cst + r * 132 + ch * 8;
                const float* bp = bias + cc;
                float4 a   = *(const float4*)(cr);
                float4 b4  = *(const float4*)(cr + 4);
                float4 ba  = *(const float4*)(bp);
                float4 bb4 = *(const float4*)(bp + 4);
                u16x8 o = { f2bf(a.x + ba.x),  f2bf(a.y + ba.y),  f2bf(a.z + ba.z),  f2bf(a.w + ba.w),
                            f2bf(b4.x + bb4.x), f2bf(b4.y + bb4.y), f2bf(b4.z + bb4.z), f2bf(b4.w + bb4.w) };
                *(u16x8*)(obf + dst) = o;
            }
        } else if (MODE == 5) {   // LN2-fold + gelu
            #pragma unroll
            for (int c = 0; c < 4; ++c) {
                int r = rr + c * 16;
                int grow = m0 + pass * 64 + r;
                float rst = stats[pass * 64 + r];
                float mrs = stats[128 + pass * 64 + r];
                const float* cr = cst + r * 132 + ch * 8;
                const float* bp = bias + n0 + ch * 8;              // b1p
                const float* sp = (const float*)addp + n0 + ch * 8; // s1
                float4 a   = *(const float4*)(cr);
                float4 b4  = *(const float4*)(cr + 4);
                float4 ba  = *(const float4*)(bp);
                float4 bb4 = *(const float4*)(bp + 4);
                float4 sa  = *(const float4*)(sp);
                float4 sb  = *(const float4*)(sp + 4);
                float x0 = gelu_t(rst * a.x - mrs * sa.x + ba.x);
                float x1 = gelu_t(rst * a.y - mrs * sa.y + ba.y);
                float x2 = gelu_t(rst * a.z - mrs * sa.z + ba.z);
                float x3 = gelu_t(rst * a.w - mrs * sa.w + ba.w);
                float x4 = gelu_t(rst * b4.x - mrs * sb.x + bb4.x);
                float x5 = gelu_t(rst * b4.y - mrs * sb.y + bb4.y);
                float x6 = gelu_t(rst * b4.z - mrs * sb.z + bb4.z);
                float x7 = gelu_t(rst * b4.w - mrs * sb.w + bb4.w);
                u16x8 o = { f2bf(x0), f2bf(x1), f2bf(x2), f2bf(x3),
                            f2bf(x4), f2bf(x5), f2bf(x6), f2bf(x7) };
                *(u16x8*)(obf + (size_t)grow * N + n0 + ch * 8) = o;
            }
        } else if (MODE == 2) {
            #pragma unroll
            for (int c = 0; c < 4; ++c) {
                int r = rr + c * 16;
                int grow = m0 + pass * 64 + r;
                int bb_ = grow >> 12, rem = grow & 4095;
                int winid = rem >> 6, tok = rem & 63;
                int wi = winid >> 3, wj = winid & 7;
                int ii = tok >> 3,  jj = tok & 7;
                int hh = (wi * 8 + ii + 4) & 63;   // roll(+4)
                int ww = (wj * 8 + jj + 4) & 63;
                size_t drow = (size_t)(bb_ << 12) + hh * 64 + ww;
                const float* cr = cst + r * 132 + ch * 8;
                const float* bp = bias + n0 + ch * 8;
                const float* res = (const float*)addp + drow * N + n0 + ch * 8;
                float4 a   = *(const float4*)(cr);
                float4 b4  = *(const float4*)(cr + 4);
                float4 ba  = *(const float4*)(bp);
                float4 bb4 = *(const float4*)(bp + 4);
                float4 ra  = *(const float4*)(res);
                float4 rb  = *(const float4*)(res + 4);
                u16x8 o = { f2bf(a.x + ba.x + ra.x),  f2bf(a.y + ba.y + ra.y),
                            f2bf(a.z + ba.z + ra.z),  f2bf(a.w + ba.w + ra.w),
                            f2bf(b4.x + bb4.x + rb.x), f2bf(b4.y + bb4.y + rb.y),
                            f2bf(b4.z + bb4.z + rb.z), f2bf(b4.w + bb4.w + rb.w) };
                *(u16x8*)(obf + drow * N + n0 + ch * 8) = o;
            }
        } else {  // MODE 3: fp32 out + bf16 residual
            #pragma unroll
            for (int c = 0; c < 8; ++c) {
                int r = rr + (c & 3) * 16;
                int grow = m0 + pass * 64 + r;
                int chunk = ch + (c >> 2) * 16;    // 0..31: float4 index within 128-col segment
                const float* cr = cst + r * 132 + chunk * 4;
                const float* bp = bias + n0 + chunk * 4;
                const unsigned short* res = (const unsigned short*)addp + (size_t)grow * N + n0 + chunk * 4;
                float4 a  = *(const float4*)(cr);
                float4 ba = *(const float4*)(bp);
                ushort4 rv = *(const ushort4*)(res);
                float4 o1 = { bfu(rv.x) + a.x + ba.x,  bfu(rv.y) + a.y + ba.y,
                              bfu(rv.z) + a.z + ba.z,  bfu(rv.w) + a.w + ba.w };
                *(float4*)(of32 + (size_t)grow * N + n0 + chunk * 4) = o1;
            }
        }
    }
}

// ---------- MFMA attention: head-major qkv [wg][sel][h][tok][32] ----------
// R14: all Q/K/V loads are contiguous 1-4KB wave-spans (was 16-line scatter at
// 1536B row stride).
#define PR 72
#define VR 72
__global__ void __launch_bounds__(256) attn_mfma(
        const unsigned short* __restrict__ qkv,
        const float* __restrict__ relt,
        unsigned short* __restrict__ ctx) {
    __shared__ float rs[1800];
    __shared__ unsigned short Pl[4][64 * PR];
    __shared__ unsigned short Vt[4][32 * VR];

    int t = threadIdx.x;
    int lane = t & 63, wave = t >> 6;
    for (int i = t; i < 1800; i += 256) rs[i] = relt[i];
    __syncthreads();

    int wh = blockIdx.x * 4 + wave;
    int wg = wh >> 3, h = wh & 7;
    int win = wg & 63;
    int ln = lane & 15, quad = lane >> 4;

    unsigned short* P = &Pl[wave][0];
    unsigned short* V = &Vt[wave][0];
    const unsigned short* bq_ = qkv + ((size_t)(wg * 3 + 0) * 8 + h) * 2048;
    const unsigned short* bk_ = qkv + ((size_t)(wg * 3 + 1) * 8 + h) * 2048;
    const unsigned short* bv_ = qkv + ((size_t)(wg * 3 + 2) * 8 + h) * 2048;

    union BF8 { bf16x8_t v; unsigned short s[8]; };
    {
        const bf16x8_t* vp = (const bf16x8_t*)(bv_ + (size_t)lane * 32);
        BF8 vv[4];
        #pragma unroll
        for (int c = 0; c < 4; ++c) vv[c].v = vp[c];
        #pragma unroll
        for (int c = 0; c < 4; ++c)
            #pragma unroll
            for (int e = 0; e < 8; ++e)
                V[(c * 8 + e) * VR + lane] = vv[c].s[e];
    }

    bf16x8_t qa[4], kb[4];
    #pragma unroll
    for (int i = 0; i < 4; ++i)
        qa[i] = *(const bf16x8_t*)(bq_ + (size_t)(i * 16 + ln) * 32 + quad * 8);
    #pragma unroll
    for (int j = 0; j < 4; ++j)
        kb[j] = *(const bf16x8_t*)(bk_ + (size_t)(j * 16 + ln) * 32 + quad * 8);

    f32x4_t acc[4][4];
    #pragma unroll
    for (int i = 0; i < 4; ++i)
        #pragma unroll
        for (int j = 0; j < 4; ++j) { acc[i][j][0]=0.f; acc[i][j][1]=0.f; acc[i][j][2]=0.f; acc[i][j][3]=0.f; }
    #pragma unroll
    for (int i = 0; i < 4; ++i)
        #pragma unroll
        for (int j = 0; j < 4; ++j)
            acc[i][j] = __builtin_amdgcn_mfma_f32_16x16x32_bf16(qa[i], kb[j], acc[i][j], 0, 0, 0);

    const float scale = 0.17677669529663687f;
    int wi = win >> 3, wj = win & 7;
    int mjv = ln & 7;
    int regm[4], mi[4];
    #pragma unroll
    for (int j = 0; j < 4; ++j) {
        mi[j] = j * 2 + (ln >> 3);
        int hm = wi * 8 + mi[j], wm = wj * 8 + mjv;
        regm[j] = (hm < 56 ? 0 : (hm < 60 ? 1 : 2)) * 3 + (wm < 56 ? 0 : (wm < 60 ? 1 : 2));
    }
    float inv[4][4];
    #pragma unroll
    for (int i = 0; i < 4; ++i) {
        #pragma unroll
        for (int e = 0; e < 4; ++e) {
            int q = i * 16 + quad * 4 + e;
            int ti = q >> 3, tj = q & 7;
            int hn = wi * 8 + ti, wn = wj * 8 + tj;
            int regn = (hn < 56 ? 0 : (hn < 60 ? 1 : 2)) * 3 + (wn < 56 ? 0 : (wn < 60 ? 1 : 2));
            float sum = 0.f;
            #pragma unroll
            for (int j = 0; j < 4; ++j) {
                float bv = rs[((ti - mi[j] + 7) * 15 + (tj - mjv + 7)) * 8 + h];
                float sv = acc[i][j][e] * scale + bv + (regm[j] != regn ? -100.f : 0.f);
                float p = __expf(sv);
                sum += p;
                P[q * PR + j * 16 + ln] = f2bf(p);
            }
            #pragma unroll
            for (int off = 1; off < 16; off <<= 1) sum += __shfl_xor(sum, off, 64);
            inv[i][e] = 1.0f / sum;
        }
    }
    __syncthreads();

    bf16x8_t vb[2][2];
    #pragma unroll
    for (int jd = 0; jd < 2; ++jd)
        #pragma unroll
        for (int kc = 0; kc < 2; ++kc)
            vb[jd][kc] = *(const bf16x8_t*)&V[(jd * 16 + ln) * VR + kc * 32 + quad * 8];
    f32x4_t occ[4][2];
    #pragma unroll
    for (int i = 0; i < 4; ++i)
        #pragma unroll
        for (int jd = 0; jd < 2; ++jd) { occ[i][jd][0]=0.f; occ[i][jd][1]=0.f; occ[i][jd][2]=0.f; occ[i][jd][3]=0.f; }
    #pragma unroll
    for (int i = 0; i < 4; ++i) {
        #pragma unroll
        for (int kc = 0; kc < 2; ++kc) {
            bf16x8_t pf = *(const bf16x8_t*)&P[(i * 16 + ln) * PR + kc * 32 + quad * 8];
            occ[i][0] = __builtin_amdgcn_mfma_f32_16x16x32_bf16(pf, vb[0][kc], occ[i][0], 0, 0, 0);
            occ[i][1] = __builtin_amdgcn_mfma_f32_16x16x32_bf16(pf, vb[1][kc], occ[i][1], 0, 0, 0);
        }
    }

    unsigned short* cbase = ctx + (size_t)wg * 64 * 256 + h * 32;
    #pragma unroll
    for (int i = 0; i < 4; ++i)
        #pragma unroll
        for (int e = 0; e < 4; ++e) {
            int q = i * 16 + quad * 4 + e;
            #pragma unroll
            for (int jd = 0; jd < 2; ++jd)
                cbase[(size_t)q * 256 + jd * 16 + ln] = f2bf(occ[i][jd][e] * inv[i][e]);
        }
}

// ---------- launch ----------
extern "C" void kernel_launch(void* const* d_in, const int* in_sizes, int n_in,
                              void* d_out, int out_size, void* d_ws, size_t ws_size,
                              hipStream_t stream) {
    const float* hs   = (const float*)d_in[0];
    const float* ln1g = (const float*)d_in[1];
    const float* ln1b = (const float*)d_in[2];
    const float* wq   = (const float*)d_in[3];
    const float* bq   = (const float*)d_in[4];
    const float* wk   = (const float*)d_in[5];
    const float* bk   = (const float*)d_in[6];
    const float* wv   = (const float*)d_in[7];
    const float* bv   = (const float*)d_in[8];
    const float* relt = (const float*)d_in[9];
    const float* wo   = (const float*)d_in[10];
    const float* bo   = (const float*)d_in[11];
    const float* ln2g = (const float*)d_in[12];
    const float* ln2b = (const float*)d_in[13];
    const float* w1   = (const float*)d_in[14];
    const float* b1   = (const float*)d_in[15];
    const float* w2   = (const float*)d_in[16];
    const float* b2   = (const float*)d_in[17];
    float* out = (float*)d_out;

    const size_t NTOK = 32768;
    size_t off = 0;
    auto carve = [&](size_t bytes) { void* p = (char*)d_ws + off; off += (bytes + 255) & ~(size_t)255; return p; };
    unsigned short* wqkv_p = (unsigned short*)carve(768ull * 256 * 2);    // fragment order
    unsigned short* wo_p   = (unsigned short*)carve(65536ull * 2);
    unsigned short* w1p    = (unsigned short*)carve(262144ull * 2);       // gamma-scaled
    unsigned short* w2p    = (unsigned short*)carve(262144ull * 2);
    float*          bqkv   = (float*)carve(768ull * 4);
    float*          s1w    = (float*)carve(1024ull * 4);
    float*          b1w    = (float*)carve(1024ull * 4);
    unsigned short* hiddenb= (unsigned short*)carve(NTOK * 256 * 2);  // bf16 residual state
    unsigned short* xw     = (unsigned short*)carve(NTOK * 256 * 2);  // LN1 out
    unsigned short* qkvb   = (unsigned short*)carve(NTOK * 768 * 2);  // head-major q|k|v
    unsigned short* cx     = (unsigned short*)carve(NTOK * 256 * 2);
    unsigned short* h1 = qkvb;   // MLP hidden [32768,1024] overlays qkv+cx (64MB)

    // 1) weights -> bf16 fragment order (w1 gamma-folded); biases; LN2-fold sums
    cvt_all<<<385, 256, 0, stream>>>(wq, wk, wv, wo, w1, w2, ln2g, bq, bk, bv, bqkv,
                                     wqkv_p, wo_p, w1p, w2p);
    prep_mlp<<<4, 256, 0, stream>>>(w1, ln2g, ln2b, b1, s1w, b1w);

    // 2) LN1 + cyclic shift + window partition -> xw (bf16)
    ln_kernel<1, 0><<<8192, 256, 0, stream>>>(hs, ln1g, ln1b, xw);

    // 3) fused QKV projection -> head-major layout
    gemm_tile<4, 256><<<dim3(256, 6), 256, 0, stream>>>(xw, wqkv_p, bqkv, 32768, 768, qkvb, nullptr, nullptr);

    // 4) windowed MFMA attention (coalesced head-major reads)
    attn_mfma<<<1024, 256, 0, stream>>>(qkvb, relt, cx);

    // 5) out projection + window reverse + unshift + fp32 residual -> hiddenb (bf16)
    gemm_tile<2, 256><<<dim3(256, 2), 256, 0, stream>>>(cx, wo_p, bo, 32768, 256, hiddenb, nullptr, hs);

    // 6+7) MLP up with LN2 folded (stats prologue) + GELU -> h1
    gemm_tile<5, 256><<<dim3(256, 8), 256, 0, stream>>>(hiddenb, w1p, b1w, 32768, 1024, h1, nullptr, s1w);

    // 8) MLP down + bf16 residual -> out (fp32)
    gemm_tile<3, 1024><<<dim3(256, 2), 256, 0, stream>>>(h1, w2p, b2, 32768, 256, nullptr, out, hiddenb);
}